// Round 1
// baseline (646.490 us; speedup 1.0000x reference)
//
#include <hip/hip_runtime.h>
#include <math.h>

#define N_MAX 4096
#define NTHR  1024

// Reduce 4 float sums across the block. scr must hold >= 64 floats.
__device__ inline void block_reduce4(float& x, float& y, float& z, float& w,
                                     volatile float* scr, int tid) {
#pragma unroll
  for (int o = 32; o > 0; o >>= 1) {
    x += __shfl_down(x, o, 64);
    y += __shfl_down(y, o, 64);
    z += __shfl_down(z, o, 64);
    w += __shfl_down(w, o, 64);
  }
  const int wv = tid >> 6, ln = tid & 63;
  __syncthreads();                       // protect scr reuse across calls
  if (ln == 0) {
    scr[wv] = x; scr[16 + wv] = y; scr[32 + wv] = z; scr[48 + wv] = w;
  }
  __syncthreads();
  if (tid == 0) {
    float sx = 0.f, sy = 0.f, sz = 0.f, sw = 0.f;
    for (int k = 0; k < NTHR / 64; ++k) {
      sx += scr[k]; sy += scr[16 + k]; sz += scr[32 + k]; sw += scr[48 + k];
    }
    scr[0] = sx; scr[16] = sy; scr[32] = sz; scr[48] = sw;
  }
  __syncthreads();
  x = scr[0]; y = scr[16]; z = scr[32]; w = scr[48];
}

__global__ __launch_bounds__(NTHR, 1)
void spearman_kernel(const float* __restrict__ pred,
                     const float* __restrict__ target,
                     float* __restrict__ out, int n) {
  __shared__ float  s_val[N_MAX];   // theta, then sorted descending
  __shared__ int    s_idx[N_MAX];   // perm (original index of sorted pos)
  __shared__ float  s_sol[N_MAX];   // isotonic solution, expanded
  __shared__ double st_sum[N_MAX];  // PAV stack: block sums (f64)
  __shared__ int    st_cnt[N_MAX];  // PAV stack: block counts
  __shared__ float  s_red[64];      // reduction scratch

  const int tid = threadIdx.x;

  // ---- Phase A: load + original-order sums: sum (p-t)^2, sum t, sum t^2 ----
  float a0 = 0.f, a1 = 0.f, a2 = 0.f;
  for (int i = tid; i < N_MAX; i += NTHR) {
    float p, t;
    if (i < n) { p = pred[i]; t = target[i]; }
    else       { p = -3.0e38f; t = 0.f; }      // pad sorts to the end (descending)
    s_val[i] = p;                              // theta = pred / 1.0
    s_idx[i] = i;
    if (i < n) {
      float d = p - t;
      a0 += d * d; a1 += t; a2 += t * t;
    }
  }
  float a3 = 0.f;
  block_reduce4(a0, a1, a2, a3, s_red, tid);   // includes barrier after LDS init

  // ---- Bitonic sort, descending by value, carrying original index ----
  for (int k = 2; k <= N_MAX; k <<= 1) {
    for (int j = k >> 1; j >= 1; j >>= 1) {
      __syncthreads();
#pragma unroll 2
      for (int t = tid; t < N_MAX / 2; t += NTHR) {
        const int l = t & (j - 1);
        const int i = ((t ^ l) << 1) | l;      // pair base; partner = i|j > i
        const int p = i | j;
        const bool up = ((i & k) == 0);
        float a = s_val[i], b = s_val[p];
        if ((a < b) == up) {                   // descending when up
          s_val[i] = b; s_val[p] = a;
          int ia = s_idx[i]; s_idx[i] = s_idx[p]; s_idx[p] = ia;
        }
      }
    }
  }
  __syncthreads();

  // ---- PAV (non-increasing isotonic fit of z[j] = s[j] - (n-j)), thread 0 ----
  if (tid == 0) {
    // Stack invariant: blocks 0..sp-2 live in LDS, top block (sp-1) in regs.
    double tsum = (double)s_val[0] - (double)n;
    int    tcnt = 1;
    int    sp = 1;
    for (int i = 1; i < n; ++i) {
      double cs = (double)s_val[i] - (double)(n - i);
      int cc = 1;
      // pool while top_mean <= cur_mean  (violation of non-increasing)
      while (sp > 0 && tsum * (double)cc <= cs * (double)tcnt) {
        cs += tsum; cc += tcnt;
        sp--;
        if (sp > 0) { tsum = st_sum[sp - 1]; tcnt = st_cnt[sp - 1]; }
      }
      if (sp > 0) { st_sum[sp - 1] = tsum; st_cnt[sp - 1] = tcnt; }
      tsum = cs; tcnt = cc; sp++;
    }
    st_sum[sp - 1] = tsum; st_cnt[sp - 1] = tcnt;  // flush top
    // Expand block means into s_sol
    int pos = 0;
    for (int b = 0; b < sp; ++b) {
      float m = (float)(st_sum[b] / (double)st_cnt[b]);
      int c = st_cnt[b];
      for (int e = 0; e < c; ++e) s_sol[pos++] = m;
    }
  }
  __syncthreads();

  // ---- Phase B: sorted-order sums of centered ranks ----
  // rs = s - sol (= ranks_sorted); center by C=(n+1)/2 (shift-invariant corr)
  const float C = 0.5f * (float)(n + 1);
  float b0 = 0.f, b1 = 0.f, b2 = 0.f, b3 = 0.f;
  for (int i = tid; i < n; i += NTHR) {
    float rc = (s_val[i] - s_sol[i]) - C;
    float t  = target[s_idx[i]];
    b0 += rc; b1 += rc * rc; b2 += rc * t;
  }
  block_reduce4(b0, b1, b2, b3, s_red, tid);

  if (tid == 0) {
    const double nn = (double)n;
    double R1 = b0, R2 = b1, RT = b2;
    double St = a1, St2 = a2;
    double cov = RT - R1 * St / nn;
    double vr  = R2 - R1 * R1 / nn;
    double vt  = St2 - St * St / nn;
    double loss = -0.1 * cov / sqrt(vr * vt) + (double)a0 / nn;
    out[0] = (float)loss;
  }
}

extern "C" void kernel_launch(void* const* d_in, const int* in_sizes, int n_in,
                              void* d_out, int out_size, void* d_ws, size_t ws_size,
                              hipStream_t stream) {
  const float* pred   = (const float*)d_in[0];
  const float* target = (const float*)d_in[1];
  float* out = (float*)d_out;
  const int n = in_sizes[0];
  spearman_kernel<<<1, NTHR, 0, stream>>>(pred, target, out, n);
}

// Round 2
// 89.922 us; speedup vs baseline: 7.1895x; 7.1895x over previous
//
#include <hip/hip_runtime.h>
#include <math.h>

#define N_MAX 4096
#define NTHR  1024
#define CS    32
#define NCHUNK (N_MAX / CS)   // 128

// Reduce 4 float sums across the block. scr must hold >= 64 floats.
__device__ inline void block_reduce4(float& x, float& y, float& z, float& w,
                                     volatile float* scr, int tid) {
#pragma unroll
  for (int o = 32; o > 0; o >>= 1) {
    x += __shfl_down(x, o, 64);
    y += __shfl_down(y, o, 64);
    z += __shfl_down(z, o, 64);
    w += __shfl_down(w, o, 64);
  }
  const int wv = tid >> 6, ln = tid & 63;
  __syncthreads();                       // protect scr reuse across calls
  if (ln == 0) {
    scr[wv] = x; scr[16 + wv] = y; scr[32 + wv] = z; scr[48 + wv] = w;
  }
  __syncthreads();
  if (tid == 0) {
    float sx = 0.f, sy = 0.f, sz = 0.f, sw = 0.f;
    for (int k = 0; k < NTHR / 64; ++k) {
      sx += scr[k]; sy += scr[16 + k]; sz += scr[32 + k]; sw += scr[48 + k];
    }
    scr[0] = sx; scr[16] = sy; scr[32] = sz; scr[48] = sw;
  }
  __syncthreads();
  x = scr[0]; y = scr[16]; z = scr[32]; w = scr[48];
}

__global__ __launch_bounds__(NTHR, 1)
void spearman_kernel(const float* __restrict__ pred,
                     const float* __restrict__ target,
                     float* __restrict__ out, int n) {
  __shared__ float  s_val[N_MAX];    // theta, then sorted descending
  __shared__ int    s_idx[N_MAX];    // perm (original index of sorted pos)
  __shared__ float  s_tp[N_MAX];     // target staged (original order)
  __shared__ float  s_q[N_MAX];      // per-block (mean + C), block-indexed
  __shared__ double st_sum[N_MAX];   // PAV stacks: block sums (f64)
  __shared__ int    st_cnt[N_MAX];   // PAV stacks: block counts
  __shared__ int    st_start[N_MAX]; // PAV stacks: block start positions
  __shared__ int    s_nb[NCHUNK];    // blocks per chunk
  __shared__ int    s_sp;            // merged block count
  __shared__ float  s_red[64];       // reduction scratch

  const int tid = threadIdx.x;

  // ---- Phase A: load + original-order sums: sum (p-t)^2, sum t, sum t^2 ----
  float a0 = 0.f, a1 = 0.f, a2 = 0.f;
  for (int i = tid; i < N_MAX; i += NTHR) {
    float p, t;
    if (i < n) { p = pred[i]; t = target[i]; }
    else       { p = -3.0e38f; t = 0.f; }      // pad sorts to the end (descending)
    s_val[i] = p;                              // theta = pred / 1.0
    s_idx[i] = i;
    s_tp[i]  = t;
    if (i < n) {
      float d = p - t;
      a0 += d * d; a1 += t; a2 += t * t;
    }
  }
  float a3 = 0.f;
  block_reduce4(a0, a1, a2, a3, s_red, tid);   // includes barrier after LDS init

  // ---- Bitonic sort, descending by value, carrying original index ----
  for (int k = 2; k <= N_MAX; k <<= 1) {
    for (int j = k >> 1; j >= 1; j >>= 1) {
      __syncthreads();
#pragma unroll 2
      for (int t = tid; t < N_MAX / 2; t += NTHR) {
        const int l = t & (j - 1);
        const int i = ((t ^ l) << 1) | l;      // pair base; partner = i|j > i
        const int p = i | j;
        const bool up = ((i & k) == 0);
        float a = s_val[i], b = s_val[p];
        if ((a < b) == up) {                   // descending when up
          s_val[i] = b; s_val[p] = a;
          int ia = s_idx[i]; s_idx[i] = s_idx[p]; s_idx[p] = ia;
        }
      }
    }
  }
  __syncthreads();

  // ---- Chunked PAV (non-increasing fit of z[j] = s[j] - (n-j)) ----
  // Stage 1: each of NCHUNK threads runs PAV on its CS-element chunk.
  // Stack lives in st_*[base..base+CS); top block cached in registers.
  if (tid < NCHUNK) {
    const int base = tid * CS;
    const int lim  = (n - base < CS) ? (n - base) : CS;
    int sp = 0;
    double tsum = 0.0; int tcnt = 0, tstart = 0;
    for (int k = 0; k < lim; ++k) {
      const int i = base + k;
      double cs_ = (double)s_val[i] - (double)(n - i);
      int cc = 1, cst = i;
      while (sp > 0 && tsum * (double)cc <= cs_ * (double)tcnt) {
        cs_ += tsum; cc += tcnt; cst = tstart;
        sp--;
        if (sp > 0) {
          tsum = st_sum[base + sp - 1]; tcnt = st_cnt[base + sp - 1];
          tstart = st_start[base + sp - 1];
        }
      }
      if (sp > 0) {
        st_sum[base + sp - 1] = tsum; st_cnt[base + sp - 1] = tcnt;
        st_start[base + sp - 1] = tstart;
      }
      tsum = cs_; tcnt = cc; tstart = cst; sp++;
    }
    if (lim > 0) {
      st_sum[base + sp - 1] = tsum; st_cnt[base + sp - 1] = tcnt;
      st_start[base + sp - 1] = tstart;
      s_nb[tid] = sp;
    } else {
      s_nb[tid] = 0;
    }
  }
  __syncthreads();

  // Stage 2: thread 0 merges chunk blocks (in-place: write idx < read idx).
  if (tid == 0) {
    int gp = 0;
    double tsum = 0.0; int tcnt = 0, tstart = 0;
    for (int c = 0; c < NCHUNK; ++c) {
      const int nb = s_nb[c], rb = c * CS;
      for (int k = 0; k < nb; ++k) {
        double cs_ = st_sum[rb + k];
        int cc = st_cnt[rb + k], cst = st_start[rb + k];
        while (gp > 0 && tsum * (double)cc <= cs_ * (double)tcnt) {
          cs_ += tsum; cc += tcnt; cst = tstart;
          gp--;
          if (gp > 0) {
            tsum = st_sum[gp - 1]; tcnt = st_cnt[gp - 1]; tstart = st_start[gp - 1];
          }
        }
        if (gp > 0) {
          st_sum[gp - 1] = tsum; st_cnt[gp - 1] = tcnt; st_start[gp - 1] = tstart;
        }
        tsum = cs_; tcnt = cc; tstart = cst; gp++;
      }
    }
    if (gp > 0) {
      st_sum[gp - 1] = tsum; st_cnt[gp - 1] = tcnt; st_start[gp - 1] = tstart;
    }
    s_sp = gp;
    // q[b] = block mean + C (small number; computed in f64, stored f32)
    const double Cd = 0.5 * (double)(n + 1);
    for (int b = 0; b < gp; ++b)
      s_q[b] = (float)(st_sum[b] / (double)st_cnt[b] + Cd);
  }
  __syncthreads();

  // ---- Phase B: sorted-order sums of centered ranks ----
  // rc = (s - sol) - C = s - q[block(i)]; block via binary search on starts.
  const int sp = s_sp;
  float b0 = 0.f, b1 = 0.f, b2 = 0.f, b3 = 0.f;
  for (int i = tid; i < n; i += NTHR) {
    int lo = 0, hi = sp - 1;
    while (lo < hi) {
      int mid = (lo + hi + 1) >> 1;
      if (st_start[mid] <= i) lo = mid; else hi = mid - 1;
    }
    float rc = s_val[i] - s_q[lo];
    float t  = s_tp[s_idx[i]];
    b0 += rc; b1 += rc * rc; b2 += rc * t;
  }
  block_reduce4(b0, b1, b2, b3, s_red, tid);

  if (tid == 0) {
    const double nn = (double)n;
    double R1 = b0, R2 = b1, RT = b2;
    double St = a1, St2 = a2;
    double cov = RT - R1 * St / nn;
    double vr  = R2 - R1 * R1 / nn;
    double vt  = St2 - St * St / nn;
    double loss = -0.1 * cov / sqrt(vr * vt) + (double)a0 / nn;
    out[0] = (float)loss;
  }
}

extern "C" void kernel_launch(void* const* d_in, const int* in_sizes, int n_in,
                              void* d_out, int out_size, void* d_ws, size_t ws_size,
                              hipStream_t stream) {
  const float* pred   = (const float*)d_in[0];
  const float* target = (const float*)d_in[1];
  float* out = (float*)d_out;
  const int n = in_sizes[0];
  spearman_kernel<<<1, NTHR, 0, stream>>>(pred, target, out, n);
}

// Round 3
// 63.123 us; speedup vs baseline: 10.2417x; 1.4245x over previous
//
#include <hip/hip_runtime.h>
#include <math.h>

#define N_MAX 4096
#define NTHR  1024
#define CS    32
#define NCHUNK (N_MAX / CS)   // 128

// K1 geometry: counting-rank sort
#define K1_TPB 256
#define EPB    16            // elements per block
#define TPE    16            // threads (parts) per element
#define IT4    (N_MAX / 4 / TPE)   // 64 float4 per thread

// Reduce 4 float sums across the block. scr must hold >= 64 floats.
__device__ inline void block_reduce4(float& x, float& y, float& z, float& w,
                                     volatile float* scr, int tid, int nthr) {
#pragma unroll
  for (int o = 32; o > 0; o >>= 1) {
    x += __shfl_down(x, o, 64);
    y += __shfl_down(y, o, 64);
    z += __shfl_down(z, o, 64);
    w += __shfl_down(w, o, 64);
  }
  const int wv = tid >> 6, ln = tid & 63;
  __syncthreads();
  if (ln == 0) {
    scr[wv] = x; scr[16 + wv] = y; scr[32 + wv] = z; scr[48 + wv] = w;
  }
  __syncthreads();
  if (tid == 0) {
    float sx = 0.f, sy = 0.f, sz = 0.f, sw = 0.f;
    for (int k = 0; k < nthr / 64; ++k) {
      sx += scr[k]; sy += scr[16 + k]; sz += scr[32 + k]; sw += scr[48 + k];
    }
    scr[0] = sx; scr[16] = sy; scr[32] = sz; scr[48] = sw;
  }
  __syncthreads();
  x = scr[0]; y = scr[16]; z = scr[32]; w = scr[48];
}

// ---- K1: counting-rank "sort". pos(e) = #{j: p_j > p_e} + #{j: p_j==p_e, j<e}
__global__ __launch_bounds__(K1_TPB)
void rank_kernel(const float* __restrict__ pred,
                 float* __restrict__ sv, int* __restrict__ sperm, int n) {
  __shared__ __align__(16) float s_p[N_MAX];
  __shared__ int s_w[4][EPB];
  const int tid = threadIdx.x;

  for (int i = tid; i < N_MAX; i += K1_TPB)
    s_p[i] = (i < n) ? pred[i] : -3.0e38f;
  __syncthreads();

  const int wv = tid >> 6, ln = tid & 63;
  const int el = ln & (EPB - 1);          // element-local 0..15
  const int sub = ln >> 4;                // 0..3
  const int part = wv * 4 + sub;          // 0..15
  const int eg = blockIdx.x * EPB + el;   // global element

  int cnt = 0;
  if (eg < n) {
    const float my = s_p[eg];
#pragma unroll 8
    for (int it = 0; it < IT4; ++it) {
      const int j4 = it * TPE + part;     // consecutive float4 across parts
      const float4 v = *(const float4*)&s_p[j4 * 4];
      const int j = j4 * 4;
      cnt += (v.x > my) || (v.x == my && (j    ) < eg);
      cnt += (v.y > my) || (v.y == my && (j + 1) < eg);
      cnt += (v.z > my) || (v.z == my && (j + 2) < eg);
      cnt += (v.w > my) || (v.w == my && (j + 3) < eg);
    }
  }
  // reduce 4 subparts within wave -> lanes 0..15
  cnt += __shfl_down(cnt, 32, 64);
  cnt += __shfl_down(cnt, 16, 64);
  if (ln < EPB) s_w[wv][ln] = cnt;
  __syncthreads();
  if (tid < EPB) {
    const int e2 = blockIdx.x * EPB + tid;
    if (e2 < n) {
      const int pos = s_w[0][tid] + s_w[1][tid] + s_w[2][tid] + s_w[3][tid];
      sv[pos] = s_p[e2];
      sperm[pos] = e2;
    }
  }
}

// ---- K2: PAV + reductions (single block) ----
__global__ __launch_bounds__(NTHR, 1)
void pav_kernel(const float* __restrict__ pred,
                const float* __restrict__ target,
                const float* __restrict__ sv, const int* __restrict__ sperm,
                float* __restrict__ out, int n) {
  __shared__ float  s_val[N_MAX];    // sorted descending
  __shared__ int    s_idx[N_MAX];    // perm
  __shared__ float  s_tp[N_MAX];     // target (original order)
  __shared__ float  s_q[N_MAX];      // per-merged-block (mean + C)
  __shared__ double st_sum[N_MAX];   // chunk stacks, then merged stack (f64)
  __shared__ int    st_cnt[N_MAX];
  __shared__ int    st_start[N_MAX];
  __shared__ int    s_nb[NCHUNK];
  __shared__ int    s_scan[NCHUNK];
  __shared__ int    s_sp;
  __shared__ float  s_red[64];

  const int tid = threadIdx.x;

  // Load sorted arrays + stage target + phase-A sums (mse, sum t, sum t^2)
  float a0 = 0.f, a1 = 0.f, a2 = 0.f;
  for (int i = tid; i < N_MAX; i += NTHR) {
    s_val[i] = (i < n) ? sv[i] : -3.0e38f;
    s_idx[i] = (i < n) ? sperm[i] : i;
    float t = 0.f;
    if (i < n) {
      const float p = pred[i];
      t = target[i];
      const float d = p - t;
      a0 += d * d; a1 += t; a2 += t * t;
    }
    s_tp[i] = t;
  }
  float a3 = 0.f;
  block_reduce4(a0, a1, a2, a3, s_red, tid, NTHR);  // barriers inside

  // Stage 1: per-chunk PAV (non-increasing fit of z[i] = s[i] - (n-i))
  if (tid < NCHUNK) {
    const int base = tid * CS;
    const int lim  = (n - base < CS) ? (n - base) : CS;
    int sp = 0;
    double tsum = 0.0; int tcnt = 0, tstart = 0;
    for (int k = 0; k < lim; ++k) {
      const int i = base + k;
      double cs_ = (double)s_val[i] - (double)(n - i);
      int cc = 1, cst = i;
      while (sp > 0 && tsum * (double)cc <= cs_ * (double)tcnt) {
        cs_ += tsum; cc += tcnt; cst = tstart;
        sp--;
        if (sp > 0) {
          tsum = st_sum[base + sp - 1]; tcnt = st_cnt[base + sp - 1];
          tstart = st_start[base + sp - 1];
        }
      }
      if (sp > 0) {
        st_sum[base + sp - 1] = tsum; st_cnt[base + sp - 1] = tcnt;
        st_start[base + sp - 1] = tstart;
      }
      tsum = cs_; tcnt = cc; tstart = cst; sp++;
    }
    if (lim > 0) {
      st_sum[base + sp - 1] = tsum; st_cnt[base + sp - 1] = tcnt;
      st_start[base + sp - 1] = tstart;
      s_nb[tid] = sp;
    } else {
      s_nb[tid] = 0;
    }
  }
  __syncthreads();

  // Inclusive scan of s_nb (two waves of 64 + carry)
  if (tid < NCHUNK) {
    int v = s_nb[tid];
#pragma unroll
    for (int d = 1; d < 64; d <<= 1) {
      const int u = __shfl_up(v, d, 64);
      if ((tid & 63) >= d) v += u;
    }
    s_scan[tid] = v;
  }
  __syncthreads();
  if (tid >= 64 && tid < NCHUNK) {
    const int carry = s_scan[63];
    s_scan[tid] += carry;
  }
  __syncthreads();

  // Stage 2: wave-0 cooperative serial merge. Lanes preload 64 blocks/batch;
  // serial pooling reads inputs via shuffle; stack reuses st_* prefix
  // (write index gp-1 < global block index -> never clobbers unconsumed data).
  if (tid < 64) {
    const int B = s_scan[NCHUNK - 1];
    double tsum = 0.0; int tcnt = 0, tstart = 0;
    int gp = 0;
    for (int basb = 0; basb < B; basb += 64) {
      double lsum = 0.0; int lcnt = 1, lstart = 0;
      const int g = basb + tid;
      if (g < B) {
        int lo = 0, hi = NCHUNK - 1;
        while (lo < hi) {
          const int mid = (lo + hi) >> 1;
          if (s_scan[mid] > g) hi = mid; else lo = mid + 1;
        }
        const int k = g - (s_scan[lo] - s_nb[lo]);
        const int a = lo * CS + k;
        lsum = st_sum[a]; lcnt = st_cnt[a]; lstart = st_start[a];
      }
      const int lim = (B - basb < 64) ? (B - basb) : 64;
      for (int r = 0; r < lim; ++r) {
        double cs_ = __shfl(lsum, r, 64);
        int cc  = __shfl(lcnt, r, 64);
        int cst = __shfl(lstart, r, 64);
        while (gp > 0 && tsum * (double)cc <= cs_ * (double)tcnt) {
          cs_ += tsum; cc += tcnt; cst = tstart;
          gp--;
          if (gp > 0) {
            tsum = st_sum[gp - 1]; tcnt = st_cnt[gp - 1]; tstart = st_start[gp - 1];
          }
        }
        if (gp > 0) {  // all lanes write identical values
          st_sum[gp - 1] = tsum; st_cnt[gp - 1] = tcnt; st_start[gp - 1] = tstart;
        }
        tsum = cs_; tcnt = cc; tstart = cst; gp++;
      }
    }
    if (B > 0) {
      st_sum[gp - 1] = tsum; st_cnt[gp - 1] = tcnt; st_start[gp - 1] = tstart;
    }
    if (tid == 0) s_sp = gp;
  }
  __syncthreads();

  // q[b] = block mean + C
  const int sp = s_sp;
  const double Cd = 0.5 * (double)(n + 1);
  for (int b = tid; b < sp; b += NTHR)
    s_q[b] = (float)(st_sum[b] / (double)st_cnt[b] + Cd);
  __syncthreads();

  // Phase B: sorted-order sums of centered ranks
  float b0 = 0.f, b1 = 0.f, b2 = 0.f, b3 = 0.f;
  for (int i = tid; i < n; i += NTHR) {
    int lo = 0, hi = sp - 1;
    while (lo < hi) {
      const int mid = (lo + hi + 1) >> 1;
      if (st_start[mid] <= i) lo = mid; else hi = mid - 1;
    }
    const float rc = s_val[i] - s_q[lo];
    const float t  = s_tp[s_idx[i]];
    b0 += rc; b1 += rc * rc; b2 += rc * t;
  }
  block_reduce4(b0, b1, b2, b3, s_red, tid, NTHR);

  if (tid == 0) {
    const double nn = (double)n;
    const double R1 = b0, R2 = b1, RT = b2;
    const double St = a1, St2 = a2;
    const double cov = RT - R1 * St / nn;
    const double vr  = R2 - R1 * R1 / nn;
    const double vt  = St2 - St * St / nn;
    const double loss = -0.1 * cov / sqrt(vr * vt) + (double)a0 / nn;
    out[0] = (float)loss;
  }
}

// ---- Fallback (R2-validated monolithic kernel) if ws is too small ----
__global__ __launch_bounds__(NTHR, 1)
void spearman_mono(const float* __restrict__ pred,
                   const float* __restrict__ target,
                   float* __restrict__ out, int n) {
  __shared__ float  s_val[N_MAX];
  __shared__ int    s_idx[N_MAX];
  __shared__ float  s_tp[N_MAX];
  __shared__ float  s_q[N_MAX];
  __shared__ double st_sum[N_MAX];
  __shared__ int    st_cnt[N_MAX];
  __shared__ int    st_start[N_MAX];
  __shared__ int    s_nb[NCHUNK];
  __shared__ int    s_sp;
  __shared__ float  s_red[64];

  const int tid = threadIdx.x;
  float a0 = 0.f, a1 = 0.f, a2 = 0.f;
  for (int i = tid; i < N_MAX; i += NTHR) {
    float p, t;
    if (i < n) { p = pred[i]; t = target[i]; }
    else       { p = -3.0e38f; t = 0.f; }
    s_val[i] = p; s_idx[i] = i; s_tp[i] = t;
    if (i < n) { const float d = p - t; a0 += d * d; a1 += t; a2 += t * t; }
  }
  float a3 = 0.f;
  block_reduce4(a0, a1, a2, a3, s_red, tid, NTHR);

  for (int k = 2; k <= N_MAX; k <<= 1) {
    for (int j = k >> 1; j >= 1; j >>= 1) {
      __syncthreads();
#pragma unroll 2
      for (int t = tid; t < N_MAX / 2; t += NTHR) {
        const int l = t & (j - 1);
        const int i = ((t ^ l) << 1) | l;
        const int p = i | j;
        const bool up = ((i & k) == 0);
        const float a = s_val[i], b = s_val[p];
        if ((a < b) == up) {
          s_val[i] = b; s_val[p] = a;
          const int ia = s_idx[i]; s_idx[i] = s_idx[p]; s_idx[p] = ia;
        }
      }
    }
  }
  __syncthreads();

  if (tid < NCHUNK) {
    const int base = tid * CS;
    const int lim  = (n - base < CS) ? (n - base) : CS;
    int sp = 0; double tsum = 0.0; int tcnt = 0, tstart = 0;
    for (int k = 0; k < lim; ++k) {
      const int i = base + k;
      double cs_ = (double)s_val[i] - (double)(n - i);
      int cc = 1, cst = i;
      while (sp > 0 && tsum * (double)cc <= cs_ * (double)tcnt) {
        cs_ += tsum; cc += tcnt; cst = tstart; sp--;
        if (sp > 0) {
          tsum = st_sum[base + sp - 1]; tcnt = st_cnt[base + sp - 1];
          tstart = st_start[base + sp - 1];
        }
      }
      if (sp > 0) {
        st_sum[base + sp - 1] = tsum; st_cnt[base + sp - 1] = tcnt;
        st_start[base + sp - 1] = tstart;
      }
      tsum = cs_; tcnt = cc; tstart = cst; sp++;
    }
    if (lim > 0) {
      st_sum[base + sp - 1] = tsum; st_cnt[base + sp - 1] = tcnt;
      st_start[base + sp - 1] = tstart; s_nb[tid] = sp;
    } else s_nb[tid] = 0;
  }
  __syncthreads();

  if (tid == 0) {
    int gp = 0; double tsum = 0.0; int tcnt = 0, tstart = 0;
    for (int c = 0; c < NCHUNK; ++c) {
      const int nb = s_nb[c], rb = c * CS;
      for (int k = 0; k < nb; ++k) {
        double cs_ = st_sum[rb + k];
        int cc = st_cnt[rb + k], cst = st_start[rb + k];
        while (gp > 0 && tsum * (double)cc <= cs_ * (double)tcnt) {
          cs_ += tsum; cc += tcnt; cst = tstart; gp--;
          if (gp > 0) {
            tsum = st_sum[gp - 1]; tcnt = st_cnt[gp - 1]; tstart = st_start[gp - 1];
          }
        }
        if (gp > 0) {
          st_sum[gp - 1] = tsum; st_cnt[gp - 1] = tcnt; st_start[gp - 1] = tstart;
        }
        tsum = cs_; tcnt = cc; tstart = cst; gp++;
      }
    }
    if (gp > 0) { st_sum[gp - 1] = tsum; st_cnt[gp - 1] = tcnt; st_start[gp - 1] = tstart; }
    s_sp = gp;
    const double Cd2 = 0.5 * (double)(n + 1);
    for (int b = 0; b < gp; ++b)
      s_q[b] = (float)(st_sum[b] / (double)st_cnt[b] + Cd2);
  }
  __syncthreads();

  const int sp = s_sp;
  float b0 = 0.f, b1 = 0.f, b2 = 0.f, b3 = 0.f;
  for (int i = tid; i < n; i += NTHR) {
    int lo = 0, hi = sp - 1;
    while (lo < hi) {
      const int mid = (lo + hi + 1) >> 1;
      if (st_start[mid] <= i) lo = mid; else hi = mid - 1;
    }
    const float rc = s_val[i] - s_q[lo];
    const float t  = s_tp[s_idx[i]];
    b0 += rc; b1 += rc * rc; b2 += rc * t;
  }
  block_reduce4(b0, b1, b2, b3, s_red, tid, NTHR);

  if (tid == 0) {
    const double nn = (double)n;
    const double cov = (double)b2 - (double)b0 * (double)a1 / nn;
    const double vr  = (double)b1 - (double)b0 * (double)b0 / nn;
    const double vt  = (double)a2 - (double)a1 * (double)a1 / nn;
    out[0] = (float)(-0.1 * cov / sqrt(vr * vt) + (double)a0 / nn);
  }
}

extern "C" void kernel_launch(void* const* d_in, const int* in_sizes, int n_in,
                              void* d_out, int out_size, void* d_ws, size_t ws_size,
                              hipStream_t stream) {
  const float* pred   = (const float*)d_in[0];
  const float* target = (const float*)d_in[1];
  float* out = (float*)d_out;
  const int n = in_sizes[0];

  const size_t need = (size_t)N_MAX * (sizeof(float) + sizeof(int));
  if (ws_size >= need) {
    float* sv   = (float*)d_ws;
    int*   sperm = (int*)((char*)d_ws + (size_t)N_MAX * sizeof(float));
    const int nb1 = (n + EPB - 1) / EPB;
    rank_kernel<<<nb1, K1_TPB, 0, stream>>>(pred, sv, sperm, n);
    pav_kernel<<<1, NTHR, 0, stream>>>(pred, target, sv, sperm, out, n);
  } else {
    spearman_mono<<<1, NTHR, 0, stream>>>(pred, target, out, n);
  }
}